// Round 3
// baseline (265.318 us; speedup 1.0000x reference)
//
#include <hip/hip_runtime.h>
#include <hip/hip_bf16.h>

// difficultyWeightedLoss: mean over N of w(t)*CE(logits[i], t[i]), C=2.
// CE = softplus(l_other - l_target); w = 1.4 if t==0 else 1.0.
//
// R3 = diagnostic round: R2's streaming loop ran at only ~2.5 TB/s effective
// (78 us for 201 MB) with no pipe saturated. This round:
//   kernel B: pure int4 streaming read of targets (67 MB) -> control for
//             achievable read BW in this harness context (~12 us if healthy).
//   kernel A: loop-free max-MLP version of the real computation: 8192 blocks,
//             each thread does 4 matched (float4 logits + int2 targets) slab
//             loads (8 samples), all loads issued before any compute.
//   kernel F: deterministic final reduce of A's 8192 partials (double acc).
//
// N = 16777216 = 8192 blocks * 256 threads * 8 samples exactly.

#define NTHR 256
#define ABLK 8192        // A: N / (256*8)
#define BBLK 2048        // B: grid-stride

__global__ __launch_bounds__(NTHR) void dwl_main_kernel(
    const float* __restrict__ logits,   // (N,2)
    const int* __restrict__ targets,    // (N,)
    float* __restrict__ partials)       // (ABLK,)
{
    const float4* lg4 = reinterpret_cast<const float4*>(logits);  // 2 samples/elem
    const int2*   tg2 = reinterpret_cast<const int2*>(targets);   // 2 samples/elem

    const int base = blockIdx.x * (4 * NTHR) + threadIdx.x;  // pair index

    // Issue all 8 loads up front (4 slabs, matched float4<->int2 granularity).
    float4 f[4];
    int2   t[4];
    #pragma unroll
    for (int k = 0; k < 4; ++k) {
        const int i = base + k * NTHR;
        f[k] = lg4[i];
        t[k] = tg2[i];
    }

    float acc = 0.0f;
    #pragma unroll
    for (int k = 0; k < 4; ++k) {
        float l0[2] = {f[k].x, f[k].z};
        float l1[2] = {f[k].y, f[k].w};
        int   tt[2] = {t[k].x, t[k].y};
        #pragma unroll
        for (int j = 0; j < 2; ++j) {
            const bool one = (tt[j] == 1);
            const float d  = one ? (l0[j] - l1[j]) : (l1[j] - l0[j]);
            const float ce = fmaxf(d, 0.0f) + __logf(1.0f + __expf(-fabsf(d)));
            acc += one ? ce : 1.4f * ce;
        }
    }

    #pragma unroll
    for (int off = 32; off > 0; off >>= 1)
        acc += __shfl_down(acc, off);

    __shared__ float smem[NTHR / 64];
    const int lane = threadIdx.x & 63;
    const int wave = threadIdx.x >> 6;
    if (lane == 0) smem[wave] = acc;
    __syncthreads();

    if (threadIdx.x == 0) {
        float s = 0.0f;
        #pragma unroll
        for (int wv = 0; wv < NTHR / 64; ++wv) s += smem[wv];
        partials[blockIdx.x] = s;
    }
}

// Control: pure streaming read of targets (67 MB), no math. Partials to ws
// (kept as a real side effect; value unused by the final reduce).
__global__ __launch_bounds__(NTHR) void dwl_stream_ctl_kernel(
    const int* __restrict__ targets,
    float* __restrict__ partials,       // (BBLK,)
    int n4)                             // N/4
{
    const int4* tg4 = reinterpret_cast<const int4*>(targets);
    const int tid    = blockIdx.x * NTHR + threadIdx.x;
    const int stride = BBLK * NTHR;

    int s = 0;
    for (int i = tid; i < n4; i += stride) {
        const int4 v = tg4[i];
        s += v.x + v.y + v.z + v.w;
    }

    float acc = (float)s;
    #pragma unroll
    for (int off = 32; off > 0; off >>= 1)
        acc += __shfl_down(acc, off);

    __shared__ float smem[NTHR / 64];
    const int lane = threadIdx.x & 63;
    const int wave = threadIdx.x >> 6;
    if (lane == 0) smem[wave] = acc;
    __syncthreads();
    if (threadIdx.x == 0) {
        float bs = 0.0f;
        #pragma unroll
        for (int wv = 0; wv < NTHR / 64; ++wv) bs += smem[wv];
        partials[blockIdx.x] = bs;
    }
}

__global__ __launch_bounds__(NTHR) void dwl_final_kernel(
    const float* __restrict__ partials,  // (ABLK,)
    float* __restrict__ out,
    float invN)
{
    double acc = 0.0;
    for (int i = threadIdx.x; i < ABLK; i += NTHR)
        acc += (double)partials[i];

    #pragma unroll
    for (int off = 32; off > 0; off >>= 1)
        acc += __shfl_down(acc, off);

    __shared__ double smem[NTHR / 64];
    const int lane = threadIdx.x & 63;
    const int wave = threadIdx.x >> 6;
    if (lane == 0) smem[wave] = acc;
    __syncthreads();

    if (threadIdx.x == 0) {
        double s = 0.0;
        #pragma unroll
        for (int wv = 0; wv < NTHR / 64; ++wv) s += smem[wv];
        out[0] = (float)(s * (double)invN);
    }
}

extern "C" void kernel_launch(void* const* d_in, const int* in_sizes, int n_in,
                              void* d_out, int out_size, void* d_ws, size_t ws_size,
                              hipStream_t stream) {
    const float* logits  = (const float*)d_in[0];
    const int*   targets = (const int*)d_in[1];
    // d_in[2] (text_keys) unused by the reference.

    const int n = in_sizes[1];                 // 16777216
    float* partA = (float*)d_ws;               // ABLK floats
    float* partB = partA + ABLK;               // BBLK floats
    float* out   = (float*)d_out;

    // B first: control inherits any harness-drain effect; A runs cleanest.
    dwl_stream_ctl_kernel<<<BBLK, NTHR, 0, stream>>>(targets, partB, n >> 2);
    dwl_main_kernel<<<ABLK, NTHR, 0, stream>>>(logits, targets, partA);
    dwl_final_kernel<<<1, NTHR, 0, stream>>>(partA, out, (float)(1.0 / (double)n));
}

// Round 5
// 246.555 us; speedup vs baseline: 1.0761x; 1.0761x over previous
//
#include <hip/hip_runtime.h>
#include <hip/hip_bf16.h>

// difficultyWeightedLoss: mean over N of w(t)*CE(logits[i], t[i]), C=2.
// CE = softplus(l_other - l_target); w = 1.4 if t==0 else 1.0.
//
// R4 theory (resubmitted — R4 bench was an infra timeout, kernel never ran):
// the harness streams ~780 MB of writes (input restores + 512 MB 0xAA
// ws-poison) through the 256 MB L3 right before our kernel, leaving L3 full
// of dirty poison lines. Normal (allocating) reads then churn the dirty L3
// and cap at ~2.6 TB/s effective. Fix: NON-TEMPORAL loads — stream reads
// without L3 allocation, like the 6.9 TB/s fill does on the write side.
//
// Structure: single loop-free main kernel (8192 blocks x 256 thr, 4 matched
// float4-logit + int2-target slabs per thread = 8 samples, all 8 loads nt and
// issued up front), block partials to ws, tiny deterministic final reduce.
// N = 16777216 = 8192 * 256 * 8 exactly.

#define NTHR 256
#define ABLK 8192

typedef float v4f __attribute__((ext_vector_type(4)));
typedef int   v2i __attribute__((ext_vector_type(2)));

__global__ __launch_bounds__(NTHR) void dwl_main_kernel(
    const float* __restrict__ logits,   // (N,2)
    const int* __restrict__ targets,    // (N,)
    float* __restrict__ partials)       // (ABLK,)
{
    const v4f* lg4 = reinterpret_cast<const v4f*>(logits);   // 2 samples/elem
    const v2i* tg2 = reinterpret_cast<const v2i*>(targets);  // 2 samples/elem

    const int base = blockIdx.x * (4 * NTHR) + threadIdx.x;  // pair index

    // All 8 loads issued up front, non-temporal (no L3 allocate).
    v4f f[4];
    v2i t[4];
    #pragma unroll
    for (int k = 0; k < 4; ++k) {
        const int i = base + k * NTHR;
        f[k] = __builtin_nontemporal_load(&lg4[i]);
        t[k] = __builtin_nontemporal_load(&tg2[i]);
    }

    float acc = 0.0f;
    #pragma unroll
    for (int k = 0; k < 4; ++k) {
        #pragma unroll
        for (int j = 0; j < 2; ++j) {
            const float l0 = f[k][2 * j];
            const float l1 = f[k][2 * j + 1];
            const bool one = (t[k][j] == 1);
            const float d  = one ? (l0 - l1) : (l1 - l0);
            const float ce = fmaxf(d, 0.0f) + __logf(1.0f + __expf(-fabsf(d)));
            acc += one ? ce : 1.4f * ce;
        }
    }

    #pragma unroll
    for (int off = 32; off > 0; off >>= 1)
        acc += __shfl_down(acc, off);

    __shared__ float smem[NTHR / 64];
    const int lane = threadIdx.x & 63;
    const int wave = threadIdx.x >> 6;
    if (lane == 0) smem[wave] = acc;
    __syncthreads();

    if (threadIdx.x == 0) {
        float s = 0.0f;
        #pragma unroll
        for (int wv = 0; wv < NTHR / 64; ++wv) s += smem[wv];
        partials[blockIdx.x] = s;
    }
}

__global__ __launch_bounds__(NTHR) void dwl_final_kernel(
    const float* __restrict__ partials,  // (ABLK,)
    float* __restrict__ out,
    float invN)
{
    double acc = 0.0;
    for (int i = threadIdx.x; i < ABLK; i += NTHR)
        acc += (double)partials[i];

    #pragma unroll
    for (int off = 32; off > 0; off >>= 1)
        acc += __shfl_down(acc, off);

    __shared__ double smem[NTHR / 64];
    const int lane = threadIdx.x & 63;
    const int wave = threadIdx.x >> 6;
    if (lane == 0) smem[wave] = acc;
    __syncthreads();

    if (threadIdx.x == 0) {
        double s = 0.0;
        #pragma unroll
        for (int wv = 0; wv < NTHR / 64; ++wv) s += smem[wv];
        out[0] = (float)(s * (double)invN);
    }
}

extern "C" void kernel_launch(void* const* d_in, const int* in_sizes, int n_in,
                              void* d_out, int out_size, void* d_ws, size_t ws_size,
                              hipStream_t stream) {
    const float* logits  = (const float*)d_in[0];
    const int*   targets = (const int*)d_in[1];
    // d_in[2] (text_keys) unused by the reference.

    const int n = in_sizes[1];                 // 16777216
    float* partials = (float*)d_ws;            // ABLK floats
    float* out      = (float*)d_out;

    dwl_main_kernel<<<ABLK, NTHR, 0, stream>>>(logits, targets, partials);
    dwl_final_kernel<<<1, NTHR, 0, stream>>>(partials, out, (float)(1.0 / (double)n));
}